// Round 2
// baseline (10146.250 us; speedup 1.0000x reference)
//
#include <hip/hip_runtime.h>
#include <math.h>

#define BB 64
#define SS 256
#define D_IN 400
#define D_RNN 200
#define HID 256
#define G4 1024   // 4*HID

// workspace layout (float offsets)
#define OFF_WTLIN 0                            // [400][200] f32
#define OFF_WTIH  (OFF_WTLIN + 400*200)        // [2][200][1024] f32
#define OFF_WHH16 (OFF_WTIH + 2*200*1024)      // [2][1024][256] f16 (262144 float slots)
#define OFF_X     (OFF_WHH16 + 2*1024*256/2)   // [2][64][256][200] f32
#define OFF_GX    (OFF_X + 2*64*256*200)       // [2][64][256][1024] f32
// overlay (xbuf is dead by the time k_lstm runs):
#define OFF_HXG   OFF_X                        // [128 seq][2 parity][256] u32(f32 bits)
#define OFF_FLAGS (OFF_X + 128*2*256)          // [256] u32

typedef _Float16 half2_t __attribute__((ext_vector_type(2)));

__device__ __forceinline__ half2_t u2h(unsigned u) {
    union { unsigned u; half2_t h; } x; x.u = u; return x.h;
}

__device__ __forceinline__ float dot2acc(unsigned hu, unsigned wu, float acc) {
#if __has_builtin(__builtin_amdgcn_fdot2)
    return __builtin_amdgcn_fdot2(u2h(hu), u2h(wu), acc, false);
#else
    half2_t h = u2h(hu), w = u2h(wu);
    acc = fmaf((float)h.x, (float)w.x, acc);
    acc = fmaf((float)h.y, (float)w.y, acc);
    return acc;
#endif
}

__device__ __forceinline__ float sigm_f(float x) {
    return 1.0f / (1.0f + __expf(-x));
}
__device__ __forceinline__ float tanh_f(float x) {
    return 2.0f / (1.0f + __expf(-2.0f * x)) - 1.0f;
}

// ---------------- transposes / packs ----------------
__global__ void kt_wlin(const float* __restrict__ W, float* __restrict__ Wt) {
    int id = blockIdx.x * 256 + threadIdx.x;
    if (id >= D_RNN * D_IN) return;
    int j = id / D_IN, k = id % D_IN;
    Wt[k * D_RNN + j] = W[id];
}

__global__ void kt_wih(const float* __restrict__ Wl, const float* __restrict__ Wr,
                       float* __restrict__ Wt) {
    int id = blockIdx.x * 256 + threadIdx.x;
    if (id >= 2 * G4 * D_RNN) return;
    int dir = id / (G4 * D_RNN);
    int r = id % (G4 * D_RNN);
    int j = r / D_RNN, k = r % D_RNN;
    const float* src = dir ? Wr : Wl;
    Wt[dir * (D_RNN * G4) + k * G4 + j] = src[r];
}

// Whh f32 [1024][256] -> f16, linear copy per dir
__global__ void kt_whh16(const float* __restrict__ Wl, const float* __restrict__ Wr,
                         _Float16* __restrict__ Wh) {
    int id = blockIdx.x * 256 + threadIdx.x;
    if (id >= 2 * G4 * HID) return;
    int dir = id / (G4 * HID);
    int r = id % (G4 * HID);
    const float* src = dir ? Wr : Wl;
    Wh[dir * (G4 * HID) + r] = (_Float16)src[r];
}

__global__ void kf_reset(unsigned* __restrict__ flags) {
    flags[threadIdx.x] = 0u;
}

// ---------------- K1: embeddings + concat + linear + tanh ----------------
__launch_bounds__(512)
__global__ void k_embed_linear(const int* __restrict__ ci, const int* __restrict__ bli,
                               const int* __restrict__ bri, const int* __restrict__ sci,
                               const int* __restrict__ sbli, const int* __restrict__ sbri,
                               const float* __restrict__ ce, const float* __restrict__ be,
                               const float* __restrict__ sce, const float* __restrict__ sbe,
                               const float* __restrict__ Wt, const float* __restrict__ blin,
                               float* __restrict__ xout) {
    __shared__ __align__(16) float vec[16][2][D_IN];
    __shared__ int idx[16][6];
    int tid = threadIdx.x;
    int g0 = blockIdx.x * 16;

    if (tid < 96) {
        int tt = tid / 6, w = tid % 6;
        int g = g0 + tt;
        const int* arr = (w == 0) ? ci : (w == 1) ? sci : (w == 2) ? bli
                         : (w == 3) ? bri : (w == 4) ? sbli : sbri;
        idx[tt][w] = arr[g];
    }
    __syncthreads();

    for (int v = tid; v < 16 * D_IN; v += 512) {
        int tt = v / D_IN, p = v % D_IN;
        float lv, rv;
        if (p < 100)      { float e = ce[idx[tt][0] * 100 + p];          lv = rv = e; }
        else if (p < 200) { float e = sce[idx[tt][1] * 100 + (p - 100)]; lv = rv = e; }
        else if (p < 300) { int q = p - 200;
                            lv = be[idx[tt][2] * 100 + q];
                            rv = be[idx[tt][3] * 100 + q]; }
        else              { int q = p - 300;
                            lv = sbe[idx[tt][4] * 100 + q];
                            rv = sbe[idx[tt][5] * 100 + q]; }
        vec[tt][0][p] = lv;
        vec[tt][1][p] = rv;
    }
    __syncthreads();

    if (tid < 400) {
        int side = tid / 200, j = tid % 200;
        float acc[16];
        #pragma unroll
        for (int t = 0; t < 16; t++) acc[t] = 0.0f;

        for (int k4 = 0; k4 < D_IN / 4; k4++) {
            float w0 = Wt[(4 * k4 + 0) * D_RNN + j];
            float w1 = Wt[(4 * k4 + 1) * D_RNN + j];
            float w2 = Wt[(4 * k4 + 2) * D_RNN + j];
            float w3 = Wt[(4 * k4 + 3) * D_RNN + j];
            #pragma unroll
            for (int t = 0; t < 16; t++) {
                float4 xv = *(const float4*)&vec[t][side][4 * k4];
                acc[t] += xv.x * w0 + xv.y * w1 + xv.z * w2 + xv.w * w3;
            }
        }
        float bias = blin[j];
        #pragma unroll
        for (int t = 0; t < 16; t++) {
            int g = g0 + t;
            int b = g >> 8, s = g & 255;
            xout[((side * BB + b) * SS + s) * D_RNN + j] = tanh_f(acc[t] + bias);
        }
    }
}

// ---------------- K2: gate-x GEMM ----------------
__launch_bounds__(512)
__global__ void k_gatex(const float* __restrict__ x, const float* __restrict__ WtIh,
                        const float* __restrict__ bihl, const float* __restrict__ bhhl,
                        const float* __restrict__ bihr, const float* __restrict__ bhhr,
                        float* __restrict__ gx) {
    __shared__ __align__(16) float xT[D_RNN][36];
    int tid = threadIdx.x;
    int id = blockIdx.x;
    int dir = id >> 9;
    int rem = id & 511;
    int b = rem >> 3;
    int s0 = (rem & 7) * 32;

    const float* xbase = x + ((dir * BB + b) * SS + s0) * D_RNN;
    for (int v = tid; v < 32 * D_RNN; v += 512) {
        int tt = v / D_RNN, k = v % D_RNN;
        xT[k][tt] = xbase[tt * D_RNN + k];
    }
    __syncthreads();

    const float* Wp = WtIh + dir * (D_RNN * G4);
    int j0 = tid, j1 = tid + 512;
    float acc0[32], acc1[32];
    #pragma unroll
    for (int t = 0; t < 32; t++) { acc0[t] = 0.0f; acc1[t] = 0.0f; }

    for (int k = 0; k < D_RNN; k++) {
        float w0 = Wp[k * G4 + j0];
        float w1 = Wp[k * G4 + j1];
        #pragma unroll
        for (int m = 0; m < 8; m++) {
            float4 xv = *(const float4*)&xT[k][4 * m];
            acc0[4 * m + 0] += xv.x * w0;
            acc0[4 * m + 1] += xv.y * w0;
            acc0[4 * m + 2] += xv.z * w0;
            acc0[4 * m + 3] += xv.w * w0;
            acc1[4 * m + 0] += xv.x * w1;
            acc1[4 * m + 1] += xv.y * w1;
            acc1[4 * m + 2] += xv.z * w1;
            acc1[4 * m + 3] += xv.w * w1;
        }
    }

    float bs0, bs1;
    if (dir) { bs0 = bihr[j0] + bhhr[j0]; bs1 = bihr[j1] + bhhr[j1]; }
    else     { bs0 = bihl[j0] + bhhl[j0]; bs1 = bihl[j1] + bhhl[j1]; }

    float* gbase = gx + ((dir * BB + b) * SS + s0) * G4;
    #pragma unroll
    for (int t = 0; t < 32; t++) {
        gbase[t * G4 + j0] = acc0[t] + bs0;
        gbase[t * G4 + j1] = acc1[t] + bs1;
    }
}

// ---------------- K3: LSTM, 2 blocks per (dir,b), pairwise h-exchange ----------------
// block bid: half=(bid>>3)&1, seq=(bid>>4)*8+(bid&7); sibling = bid^8 (same XCD slot).
// thread t: q=t>>7 (gate i/f/g/o), j=t&127; gate col c=q*256+half*128+j.
// Weights Whh[c][0:256] held as 128 packed-f16 VGPRs. h broadcast via LDS.
__launch_bounds__(512, 2)
__global__ void k_lstm(const _Float16* __restrict__ whh16, const float* __restrict__ gx,
                       float* __restrict__ out, unsigned* __restrict__ hxg,
                       unsigned* __restrict__ flags) {
    __shared__ __align__(16) unsigned short h16a[HID];   // h as f16, full 256
    __shared__ float gl[512];                            // gates staging

    int t = threadIdx.x;
    int bid = blockIdx.x;
    int half = (bid >> 3) & 1;
    int seq = ((bid >> 4) << 3) | (bid & 7);    // [0,128)
    int dir = seq >> 6, b = seq & 63;
    int q = t >> 7, j = t & 127;
    int c = q * 256 + half * 128 + j;
    int jh = half * 128 + j;                    // h col owned (t<128)

    // load weights: 32 x uint4 = 128 half2
    const uint4* wb = reinterpret_cast<const uint4*>(whh16 + (size_t)(dir * G4 + c) * HID);
    uint4 wr[32];
    #pragma unroll
    for (int i = 0; i < 32; i++) wr[i] = wb[i];

    const float* gxp = gx + (size_t)(dir * BB + b) * SS * G4;
    float* outp = out + (size_t)b * SS * (2 * HID) + dir * HID + jh;
    unsigned* hxs = hxg + seq * 512;            // [2 parity][256]
    int ownf = bid, sibf = bid ^ 8;

    if (t < HID) h16a[t] = 0;
    float cst = 0.0f;
    __syncthreads();

    int ts = dir ? (SS - 1) : 0;
    int ds = dir ? -1 : 1;
    float gxv = gxp[(size_t)ts * G4 + c];

    const uint4* hv = reinterpret_cast<const uint4*>(h16a);

    for (int s = 0; s < SS; s++) {
        // prefetch next step's gx
        float gxn = 0.0f;
        if (s < SS - 1) gxn = gxp[(size_t)(ts + ds) * G4 + c];

        // gates = gx + Whh[c] . h
        float a0 = gxv, a1 = 0.0f, a2 = 0.0f, a3 = 0.0f;
        #pragma unroll
        for (int i = 0; i < 32; i++) {
            uint4 h4 = hv[i];
            a0 = dot2acc(h4.x, wr[i].x, a0);
            a1 = dot2acc(h4.y, wr[i].y, a1);
            a2 = dot2acc(h4.z, wr[i].z, a2);
            a3 = dot2acc(h4.w, wr[i].w, a3);
        }
        gl[t] = (a0 + a1) + (a2 + a3);
        __syncthreads();

        if (t < HID / 2 * 1) { /* t<128 */ }
        if (t < 128) {
            float ig = sigm_f(gl[t]);
            float fg = sigm_f(gl[t + 128]);
            float gg = tanh_f(gl[t + 256]);
            float og = sigm_f(gl[t + 384]);
            cst = fg * cst + ig * gg;
            float hh = og * tanh_f(cst);
            outp[(size_t)ts * (2 * HID)] = hh;
            __hip_atomic_store(&hxs[(s & 1) * 256 + jh], __float_as_uint(hh),
                               __ATOMIC_RELAXED, __HIP_MEMORY_SCOPE_AGENT);
            h16a[jh] = (unsigned short)__builtin_bit_cast(unsigned short, (_Float16)hh);
            __threadfence();
        }
        __syncthreads();

        if (t == 0) {
            __hip_atomic_store(&flags[ownf], (unsigned)(s + 1),
                               __ATOMIC_RELEASE, __HIP_MEMORY_SCOPE_AGENT);
        }
        // all threads spin for sibling
        for (;;) {
            unsigned v = __hip_atomic_load(&flags[sibf], __ATOMIC_ACQUIRE,
                                           __HIP_MEMORY_SCOPE_AGENT);
            if (v >= (unsigned)(s + 1)) break;
            __builtin_amdgcn_s_sleep(1);
        }
        if (t < 128) {
            int jo = (half ^ 1) * 128 + j;      // sibling's h col
            unsigned u = __hip_atomic_load(&hxs[(s & 1) * 256 + jo], __ATOMIC_RELAXED,
                                           __HIP_MEMORY_SCOPE_AGENT);
            float hs = __uint_as_float(u);
            h16a[jo] = (unsigned short)__builtin_bit_cast(unsigned short, (_Float16)hs);
        }
        __syncthreads();

        gxv = gxn;
        ts += ds;
    }
}

extern "C" void kernel_launch(void* const* d_in, const int* in_sizes, int n_in,
                              void* d_out, int out_size, void* d_ws, size_t ws_size,
                              hipStream_t stream) {
    const int* char_features      = (const int*)d_in[0];
    const int* bichar_left        = (const int*)d_in[1];
    const int* bichar_right       = (const int*)d_in[2];
    const int* static_char        = (const int*)d_in[3];
    const int* static_bichar_left = (const int*)d_in[4];
    const int* static_bichar_right= (const int*)d_in[5];
    const float* char_emb         = (const float*)d_in[6];
    const float* bichar_emb       = (const float*)d_in[7];
    const float* static_char_emb  = (const float*)d_in[8];
    const float* static_bichar_emb= (const float*)d_in[9];
    const float* W_lin            = (const float*)d_in[10];
    const float* b_lin            = (const float*)d_in[11];
    const float* Wih_l            = (const float*)d_in[12];
    const float* Whh_l            = (const float*)d_in[13];
    const float* bih_l            = (const float*)d_in[14];
    const float* bhh_l            = (const float*)d_in[15];
    const float* Wih_r            = (const float*)d_in[16];
    const float* Whh_r            = (const float*)d_in[17];
    const float* bih_r            = (const float*)d_in[18];
    const float* bhh_r            = (const float*)d_in[19];

    float* ws    = (float*)d_ws;
    float* wtlin = ws + OFF_WTLIN;
    float* wtih  = ws + OFF_WTIH;
    _Float16* whh16 = (_Float16*)(ws + OFF_WHH16);
    float* xbuf  = ws + OFF_X;
    float* gxbuf = ws + OFF_GX;
    unsigned* hxg   = (unsigned*)(ws + OFF_HXG);
    unsigned* flags = (unsigned*)(ws + OFF_FLAGS);
    float* out   = (float*)d_out;

    kt_wlin<<<(D_RNN * D_IN + 255) / 256, 256, 0, stream>>>(W_lin, wtlin);
    kt_wih<<<(2 * G4 * D_RNN + 255) / 256, 256, 0, stream>>>(Wih_l, Wih_r, wtih);
    kt_whh16<<<(2 * G4 * HID + 255) / 256, 256, 0, stream>>>(Whh_l, Whh_r, whh16);

    k_embed_linear<<<(BB * SS) / 16, 512, 0, stream>>>(
        char_features, bichar_left, bichar_right, static_char,
        static_bichar_left, static_bichar_right,
        char_emb, bichar_emb, static_char_emb, static_bichar_emb,
        wtlin, b_lin, xbuf);

    k_gatex<<<(2 * BB * SS) / 32, 512, 0, stream>>>(
        xbuf, wtih, bih_l, bhh_l, bih_r, bhh_r, gxbuf);

    kf_reset<<<1, 256, 0, stream>>>(flags);

    k_lstm<<<2 * BB * 2, 512, 0, stream>>>(whh16, gxbuf, out, hxg, flags);
}

// Round 3
// 825.941 us; speedup vs baseline: 12.2845x; 12.2845x over previous
//
#include <hip/hip_runtime.h>
#include <math.h>

#define BB 64
#define SS 256
#define D_IN 400
#define D_RNN 200
#define HID 256
#define G4 1024   // 4*HID

#define RHALF 92   // half2 weights in VGPRs  (k in [0,184))
#define LHALF 36   // half2 weights in LDS    (k in [184,256))  -> 9 uint4

// workspace layout (float offsets)
#define OFF_WTLIN 0                            // [400][200] f32
#define OFF_WTIH  (OFF_WTLIN + 400*200)        // [2][200][1024] f32
#define OFF_WHH16 (OFF_WTIH + 2*200*1024)      // [2][1024][256] f16
#define OFF_X     (OFF_WHH16 + 2*1024*256/2)   // [2][64][256][200] f32
#define OFF_GX    (OFF_X + 2*64*256*200)       // [2][64][256][1024] f32

typedef _Float16 half2_t __attribute__((ext_vector_type(2)));

__device__ __forceinline__ half2_t u2h(unsigned u) {
    union { unsigned u; half2_t h; } x; x.u = u; return x.h;
}

__device__ __forceinline__ float dot2acc(unsigned hu, unsigned wu, float acc) {
#if __has_builtin(__builtin_amdgcn_fdot2)
    return __builtin_amdgcn_fdot2(u2h(hu), u2h(wu), acc, false);
#else
    half2_t h = u2h(hu), w = u2h(wu);
    acc = fmaf((float)h.x, (float)w.x, acc);
    acc = fmaf((float)h.y, (float)w.y, acc);
    return acc;
#endif
}

__device__ __forceinline__ float sigm_f(float x) {
    return 1.0f / (1.0f + __expf(-x));
}
__device__ __forceinline__ float tanh_f(float x) {
    return 2.0f / (1.0f + __expf(-2.0f * x)) - 1.0f;
}

// ---------------- transposes / packs ----------------
__global__ void kt_wlin(const float* __restrict__ W, float* __restrict__ Wt) {
    int id = blockIdx.x * 256 + threadIdx.x;
    if (id >= D_RNN * D_IN) return;
    int j = id / D_IN, k = id % D_IN;
    Wt[k * D_RNN + j] = W[id];
}

__global__ void kt_wih(const float* __restrict__ Wl, const float* __restrict__ Wr,
                       float* __restrict__ Wt) {
    int id = blockIdx.x * 256 + threadIdx.x;
    if (id >= 2 * G4 * D_RNN) return;
    int dir = id / (G4 * D_RNN);
    int r = id % (G4 * D_RNN);
    int j = r / D_RNN, k = r % D_RNN;
    const float* src = dir ? Wr : Wl;
    Wt[dir * (D_RNN * G4) + k * G4 + j] = src[r];
}

// Whh f32 [1024][256] -> f16 [dir][c][k] (same layout, cast only)
__global__ void kt_whh16(const float* __restrict__ Wl, const float* __restrict__ Wr,
                         _Float16* __restrict__ Wh) {
    int id = blockIdx.x * 256 + threadIdx.x;
    if (id >= 2 * G4 * HID) return;
    int dir = id / (G4 * HID);
    int r = id % (G4 * HID);
    const float* src = dir ? Wr : Wl;
    Wh[dir * (G4 * HID) + r] = (_Float16)src[r];
}

// ---------------- K1: embeddings + concat + linear + tanh ----------------
__launch_bounds__(512)
__global__ void k_embed_linear(const int* __restrict__ ci, const int* __restrict__ bli,
                               const int* __restrict__ bri, const int* __restrict__ sci,
                               const int* __restrict__ sbli, const int* __restrict__ sbri,
                               const float* __restrict__ ce, const float* __restrict__ be,
                               const float* __restrict__ sce, const float* __restrict__ sbe,
                               const float* __restrict__ Wt, const float* __restrict__ blin,
                               float* __restrict__ xout) {
    __shared__ __align__(16) float vec[16][2][D_IN];
    __shared__ int idx[16][6];
    int tid = threadIdx.x;
    int g0 = blockIdx.x * 16;

    if (tid < 96) {
        int tt = tid / 6, w = tid % 6;
        int g = g0 + tt;
        const int* arr = (w == 0) ? ci : (w == 1) ? sci : (w == 2) ? bli
                         : (w == 3) ? bri : (w == 4) ? sbli : sbri;
        idx[tt][w] = arr[g];
    }
    __syncthreads();

    for (int v = tid; v < 16 * D_IN; v += 512) {
        int tt = v / D_IN, p = v % D_IN;
        float lv, rv;
        if (p < 100)      { float e = ce[idx[tt][0] * 100 + p];          lv = rv = e; }
        else if (p < 200) { float e = sce[idx[tt][1] * 100 + (p - 100)]; lv = rv = e; }
        else if (p < 300) { int q = p - 200;
                            lv = be[idx[tt][2] * 100 + q];
                            rv = be[idx[tt][3] * 100 + q]; }
        else              { int q = p - 300;
                            lv = sbe[idx[tt][4] * 100 + q];
                            rv = sbe[idx[tt][5] * 100 + q]; }
        vec[tt][0][p] = lv;
        vec[tt][1][p] = rv;
    }
    __syncthreads();

    if (tid < 400) {
        int side = tid / 200, j = tid % 200;
        float acc[16];
        #pragma unroll
        for (int t = 0; t < 16; t++) acc[t] = 0.0f;

        for (int k4 = 0; k4 < D_IN / 4; k4++) {
            float w0 = Wt[(4 * k4 + 0) * D_RNN + j];
            float w1 = Wt[(4 * k4 + 1) * D_RNN + j];
            float w2 = Wt[(4 * k4 + 2) * D_RNN + j];
            float w3 = Wt[(4 * k4 + 3) * D_RNN + j];
            #pragma unroll
            for (int t = 0; t < 16; t++) {
                float4 xv = *(const float4*)&vec[t][side][4 * k4];
                acc[t] += xv.x * w0 + xv.y * w1 + xv.z * w2 + xv.w * w3;
            }
        }
        float bias = blin[j];
        #pragma unroll
        for (int t = 0; t < 16; t++) {
            int g = g0 + t;
            int b = g >> 8, s = g & 255;
            xout[((side * BB + b) * SS + s) * D_RNN + j] = tanh_f(acc[t] + bias);
        }
    }
}

// ---------------- K2: gate-x GEMM ----------------
__launch_bounds__(512)
__global__ void k_gatex(const float* __restrict__ x, const float* __restrict__ WtIh,
                        const float* __restrict__ bihl, const float* __restrict__ bhhl,
                        const float* __restrict__ bihr, const float* __restrict__ bhhr,
                        float* __restrict__ gx) {
    __shared__ __align__(16) float xT[D_RNN][36];
    int tid = threadIdx.x;
    int id = blockIdx.x;
    int dir = id >> 9;
    int rem = id & 511;
    int b = rem >> 3;
    int s0 = (rem & 7) * 32;

    const float* xbase = x + ((dir * BB + b) * SS + s0) * D_RNN;
    for (int v = tid; v < 32 * D_RNN; v += 512) {
        int tt = v / D_RNN, k = v % D_RNN;
        xT[k][tt] = xbase[tt * D_RNN + k];
    }
    __syncthreads();

    const float* Wp = WtIh + dir * (D_RNN * G4);
    int j0 = tid, j1 = tid + 512;
    float acc0[32], acc1[32];
    #pragma unroll
    for (int t = 0; t < 32; t++) { acc0[t] = 0.0f; acc1[t] = 0.0f; }

    for (int k = 0; k < D_RNN; k++) {
        float w0 = Wp[k * G4 + j0];
        float w1 = Wp[k * G4 + j1];
        #pragma unroll
        for (int m = 0; m < 8; m++) {
            float4 xv = *(const float4*)&xT[k][4 * m];
            acc0[4 * m + 0] += xv.x * w0;
            acc0[4 * m + 1] += xv.y * w0;
            acc0[4 * m + 2] += xv.z * w0;
            acc0[4 * m + 3] += xv.w * w0;
            acc1[4 * m + 0] += xv.x * w1;
            acc1[4 * m + 1] += xv.y * w1;
            acc1[4 * m + 2] += xv.z * w1;
            acc1[4 * m + 3] += xv.w * w1;
        }
    }

    float bs0, bs1;
    if (dir) { bs0 = bihr[j0] + bhhr[j0]; bs1 = bihr[j1] + bhhr[j1]; }
    else     { bs0 = bihl[j0] + bhhl[j0]; bs1 = bihl[j1] + bhhl[j1]; }

    float* gbase = gx + ((dir * BB + b) * SS + s0) * G4;
    #pragma unroll
    for (int t = 0; t < 32; t++) {
        gbase[t * G4 + j0] = acc0[t] + bs0;
        gbase[t * G4 + j1] = acc1[t] + bs1;
    }
}

// ---------------- K3: LSTM, ONE block per (dir,b). Zero inter-block sync. ----------------
// 1024 threads; thread t owns gate column t. Whh[t][0:184) in 92 half2 VGPRs,
// Whh[t][184:256) in LDS ([9][1024] uint4, lane-contiguous 16B => conflict-free).
// h (256 f16) broadcast from LDS.
__launch_bounds__(1024)
__global__ void k_lstm(const _Float16* __restrict__ whh16, const float* __restrict__ gx,
                       float* __restrict__ out) {
    __shared__ __align__(16) unsigned wlds[9][1024][4];   // 147456 B
    __shared__ float gl[G4];                              // 4096 B
    __shared__ __align__(16) unsigned short hbuf[HID];    // 512 B

    int t = threadIdx.x;
    int bid = blockIdx.x;           // 128
    int dir = bid >> 6, b = bid & 63;

    // ---- load weights ----
    const uint4* wrow = reinterpret_cast<const uint4*>(whh16 + (size_t)(dir * G4 + t) * HID);
    unsigned wr[RHALF];             // 23 uint4
    #pragma unroll
    for (int i = 0; i < 23; i++) {
        uint4 v = wrow[i];
        wr[4 * i + 0] = v.x; wr[4 * i + 1] = v.y;
        wr[4 * i + 2] = v.z; wr[4 * i + 3] = v.w;
    }
    #pragma unroll
    for (int i = 0; i < 9; i++) {
        uint4 v = wrow[23 + i];
        *reinterpret_cast<uint4*>(&wlds[i][t][0]) = v;
    }

    const float* gxp = gx + (size_t)(dir * BB + b) * SS * G4;
    float* outp = out + (size_t)b * SS * (2 * HID) + dir * HID + t;   // valid for t<256

    if (t < HID) hbuf[t] = 0;
    float cst = 0.0f;
    __syncthreads();

    int ts = dir ? (SS - 1) : 0;
    int dstep = dir ? -1 : 1;
    float gxv = gxp[(size_t)ts * G4 + t];
    int q = t >> 8;                 // gate id (wave-uniform)

    const uint4* h4 = reinterpret_cast<const uint4*>(hbuf);

    for (int s = 0; s < SS; s++) {
        // prefetch next step's gx early (hidden under dot products)
        float gxn = 0.0f;
        if (s < SS - 1) gxn = gxp[(size_t)(ts + dstep) * G4 + t];

        // gate = gx + Whh[t] . h
        float a0 = gxv, a1 = 0.0f, a2 = 0.0f, a3 = 0.0f;
        #pragma unroll
        for (int i = 0; i < 23; i++) {
            uint4 hh = h4[i];
            a0 = dot2acc(hh.x, wr[4 * i + 0], a0);
            a1 = dot2acc(hh.y, wr[4 * i + 1], a1);
            a2 = dot2acc(hh.z, wr[4 * i + 2], a2);
            a3 = dot2acc(hh.w, wr[4 * i + 3], a3);
        }
        #pragma unroll
        for (int i = 0; i < 9; i++) {
            uint4 wv = *reinterpret_cast<const uint4*>(&wlds[i][t][0]);
            uint4 hh = h4[23 + i];
            a0 = dot2acc(hh.x, wv.x, a0);
            a1 = dot2acc(hh.y, wv.y, a1);
            a2 = dot2acc(hh.z, wv.z, a2);
            a3 = dot2acc(hh.w, wv.w, a3);
        }
        float gate = (a0 + a1) + (a2 + a3);

        // per-gate nonlinearity, distributed across all 1024 threads (wave-uniform q)
        gl[t] = (q == 2) ? tanh_f(gate) : sigm_f(gate);
        __syncthreads();

        if (t < HID) {
            float ig = gl[t];
            float fg = gl[t + 256];
            float gg = gl[t + 512];
            float og = gl[t + 768];
            cst = fg * cst + ig * gg;
            float hh = og * tanh_f(cst);
            outp[(size_t)ts * (2 * HID)] = hh;
            hbuf[t] = __builtin_bit_cast(unsigned short, (_Float16)hh);
        }
        __syncthreads();

        gxv = gxn;
        ts += dstep;
    }
}

extern "C" void kernel_launch(void* const* d_in, const int* in_sizes, int n_in,
                              void* d_out, int out_size, void* d_ws, size_t ws_size,
                              hipStream_t stream) {
    const int* char_features      = (const int*)d_in[0];
    const int* bichar_left        = (const int*)d_in[1];
    const int* bichar_right       = (const int*)d_in[2];
    const int* static_char        = (const int*)d_in[3];
    const int* static_bichar_left = (const int*)d_in[4];
    const int* static_bichar_right= (const int*)d_in[5];
    const float* char_emb         = (const float*)d_in[6];
    const float* bichar_emb       = (const float*)d_in[7];
    const float* static_char_emb  = (const float*)d_in[8];
    const float* static_bichar_emb= (const float*)d_in[9];
    const float* W_lin            = (const float*)d_in[10];
    const float* b_lin            = (const float*)d_in[11];
    const float* Wih_l            = (const float*)d_in[12];
    const float* Whh_l            = (const float*)d_in[13];
    const float* bih_l            = (const float*)d_in[14];
    const float* bhh_l            = (const float*)d_in[15];
    const float* Wih_r            = (const float*)d_in[16];
    const float* Whh_r            = (const float*)d_in[17];
    const float* bih_r            = (const float*)d_in[18];
    const float* bhh_r            = (const float*)d_in[19];

    float* ws    = (float*)d_ws;
    float* wtlin = ws + OFF_WTLIN;
    float* wtih  = ws + OFF_WTIH;
    _Float16* whh16 = (_Float16*)(ws + OFF_WHH16);
    float* xbuf  = ws + OFF_X;
    float* gxbuf = ws + OFF_GX;
    float* out   = (float*)d_out;

    kt_wlin<<<(D_RNN * D_IN + 255) / 256, 256, 0, stream>>>(W_lin, wtlin);
    kt_wih<<<(2 * G4 * D_RNN + 255) / 256, 256, 0, stream>>>(Wih_l, Wih_r, wtih);
    kt_whh16<<<(2 * G4 * HID + 255) / 256, 256, 0, stream>>>(Whh_l, Whh_r, whh16);

    k_embed_linear<<<(BB * SS) / 16, 512, 0, stream>>>(
        char_features, bichar_left, bichar_right, static_char,
        static_bichar_left, static_bichar_right,
        char_emb, bichar_emb, static_char_emb, static_bichar_emb,
        wtlin, b_lin, xbuf);

    k_gatex<<<(2 * BB * SS) / 32, 512, 0, stream>>>(
        xbuf, wtih, bih_l, bhh_l, bih_r, bhh_r, gxbuf);

    k_lstm<<<2 * BB, 1024, 0, stream>>>(whh16, gxbuf, out);
}